// Round 4
// baseline (1086.127 us; speedup 1.0000x reference)
//
#include <hip/hip_runtime.h>

// ---------------------------------------------------------------------------
// GCN 2-layer forward, round 4.
// CSR build rewritten as 2-level bucketed counting sort (256 nodes/bucket):
//   k_binit  : bcnt[b] = #nodes in bucket (pre-counts self loops)
//   k_bcount : LDS histogram of edge destinations by bucket -> bcnt
//   k_bscan  : exclusive scan of bucket counts -> boff, bcur
//   k_part   : scatter packed (src | (col&255)<<24) into bucket regions
//              (write frontier = 391 cachelines -> L2 merges -> ~7MB writeback
//               vs 109MB for the old full-random scatter)
//   k_bfill  : block per bucket: LDS node histogram + scan -> offsets/cnt/dinv,
//              then LDS-cursor fill of csrc (17KB write window per block)
// Features stay packed bf16; norm folded into GEMM/agg epilogues.
// ---------------------------------------------------------------------------

#define WPB 4      // waves per block (gemm/agg)
#define BSH 8      // bucket shift: 256 nodes per bucket
#define BSZ 256

__device__ __forceinline__ unsigned bf16_rne(float f) {
    unsigned b = __float_as_uint(f);
    return (b + 0x7fffu + ((b >> 16) & 1u)) >> 16;
}
__device__ __forceinline__ float bf16_lo(unsigned u) { return __uint_as_float(u << 16); }
__device__ __forceinline__ float bf16_hi(unsigned u) { return __uint_as_float(u & 0xffff0000u); }

__global__ void k_binit(int* __restrict__ bcnt, int NB, int N) {
    int b = blockIdx.x * blockDim.x + threadIdx.x;
    if (b < NB) {
        int lo = b << BSH;
        int hi = min(N, lo + BSZ);
        bcnt[b] = hi - lo;  // self loops pre-counted
    }
}

__global__ __launch_bounds__(256) void k_bcount(const int* __restrict__ col, int E,
                                                int* __restrict__ bcnt, int NB) {
    __shared__ int hist[512];
    int t = threadIdx.x;
    for (int i = t; i < NB; i += 256) hist[i] = 0;
    __syncthreads();
    int i = blockIdx.x * blockDim.x + t;
    int stride = gridDim.x * blockDim.x;
    for (; i < E; i += stride) {
        atomicAdd(&hist[col[i] >> BSH], 1);
    }
    __syncthreads();
    for (int b = t; b < NB; b += 256) {
        int h = hist[b];
        if (h) atomicAdd(&bcnt[b], h);
    }
}

// Single block: exclusive scan of NB (<=512) bucket counts.
__global__ void k_bscan(const int* __restrict__ bcnt, int NB,
                        int* __restrict__ boff, int* __restrict__ bcur) {
    __shared__ int sh[513];
    int t = threadIdx.x;
    for (int i = t; i < NB; i += blockDim.x) sh[i] = bcnt[i];
    __syncthreads();
    if (t == 0) {
        int run = 0;
        for (int i = 0; i < NB; i++) { int v = sh[i]; sh[i] = run; run += v; }
        sh[NB] = run;
    }
    __syncthreads();
    for (int i = t; i <= NB; i += blockDim.x) boff[i] = sh[i];
    for (int i = t; i < NB; i += blockDim.x) bcur[i] = sh[i];
}

// Scatter messages into bucket regions. pk = src | (col&255)<<24.
__global__ __launch_bounds__(256) void k_part(const int* __restrict__ rowi,
                                              const int* __restrict__ coli,
                                              int E, int N, int* __restrict__ bcur,
                                              unsigned* __restrict__ pairs) {
    int i = blockIdx.x * blockDim.x + threadIdx.x;
    int stride = gridDim.x * blockDim.x;
    int T = E + N;
    for (; i < T; i += stride) {
        int r, c;
        if (i < E) { r = rowi[i]; c = coli[i]; }
        else       { r = i - E; c = r; }  // self loop
        int slot = atomicAdd(&bcur[c >> BSH], 1);
        pairs[slot] = (unsigned)r | ((unsigned)(c & (BSZ - 1)) << 24);
    }
}

// One block per bucket: histogram its <=256 nodes, scan, emit CSR meta, fill csrc.
__global__ __launch_bounds__(256) void k_bfill(const unsigned* __restrict__ pairs,
                                               const int* __restrict__ boff,
                                               int N,
                                               int* __restrict__ offsets,
                                               int* __restrict__ cnt,
                                               float* __restrict__ dinv,
                                               int* __restrict__ csrc) {
    __shared__ int scnt[BSZ];
    __shared__ int scur[BSZ];
    __shared__ int wsum[4];
    int b = blockIdx.x;
    int t = threadIdx.x;
    int ebeg = boff[b];
    int m = boff[b + 1] - ebeg;
    scnt[t] = 0;
    __syncthreads();
    for (int i = t; i < m; i += 256) {
        atomicAdd(&scnt[pairs[ebeg + i] >> 24], 1);
    }
    __syncthreads();
    int cval = scnt[t];
    // block exclusive scan of scnt
    int lane = t & 63, wid = t >> 6;
    int inc = cval;
    #pragma unroll
    for (int d = 1; d < 64; d <<= 1) {
        int o = __shfl_up(inc, d);
        if (lane >= d) inc += o;
    }
    if (lane == 63) wsum[wid] = inc;
    __syncthreads();
    int woff = 0;
    for (int i = 0; i < wid; i++) woff += wsum[i];
    int off = ebeg + woff + inc - cval;  // global CSR offset for node (b<<BSH)+t
    int v = (b << BSH) + t;
    if (v < N) {
        offsets[v] = off;
        cnt[v] = cval;
        dinv[v] = rsqrtf((float)cval);  // cval >= 1 (self loop)
    }
    scur[t] = off;
    __syncthreads();
    for (int i = t; i < m; i += 256) {
        unsigned pk = pairs[ebeg + i];
        int slot = atomicAdd(&scur[pk >> 24], 1);
        csrc[slot] = (int)(pk & 0xFFFFFFu);
    }
}

// H[row] = dinv[row] * (X[row] @ W), output packed bf16 (32 uints/row).
template <bool BF16IN>
__global__ __launch_bounds__(256) void k_gemm(const void* __restrict__ Xv,
                                              const float* __restrict__ W,
                                              const float* __restrict__ dinv,
                                              unsigned* __restrict__ Hout,
                                              int N, int totalWaves) {
    __shared__ float Ws[64 * 64];
    int t = threadIdx.x;
    {
        const float4* W4 = (const float4*)W;
        float4* Ws4 = (float4*)Ws;
        for (int i = t; i < 1024; i += 256) Ws4[i] = W4[i];
    }
    __syncthreads();
    int lane = t & 63;
    int wave = blockIdx.x * WPB + (t >> 6);
    for (int row = wave; row < N; row += totalWaves) {
        float f0, f1 = 0.f;
        if (BF16IN) {
            const unsigned* A = (const unsigned*)Xv;
            unsigned u = A[(size_t)row * 32 + (lane & 31)];
            f0 = bf16_lo(u); f1 = bf16_hi(u);
        } else {
            const float* X = (const float*)Xv;
            f0 = X[(size_t)row * 64 + lane];
        }
        float acc = 0.f;
        #pragma unroll
        for (int k = 0; k < 64; k++) {
            float xk = BF16IN ? __shfl((k & 1) ? f1 : f0, k >> 1)
                              : __shfl(f0, k);
            acc = fmaf(xk, Ws[k * 64 + lane], acc);
        }
        float val = acc * dinv[row];
        float p0 = __shfl(val, (lane & 31) * 2);
        float p1 = __shfl(val, (lane & 31) * 2 + 1);
        if (lane < 32) {
            Hout[(size_t)row * 32 + lane] = bf16_rne(p0) | (bf16_rne(p1) << 16);
        }
    }
}

// out[v] = epi( dinv[v] * sum_{j in CSR[v]} H[src_j] + bias )
template <bool RELU_BF16OUT>
__global__ __launch_bounds__(256) void k_agg(const uint2* __restrict__ H,
                                             const int* __restrict__ offsets,
                                             const int* __restrict__ cnt,
                                             const int* __restrict__ csrc,
                                             const float* __restrict__ dinv,
                                             const float* __restrict__ bias,
                                             void* __restrict__ outv, int N) {
    int t = threadIdx.x;
    int lane = t & 63;
    int q = lane >> 4;    // quarter 0..3 -> edge j+q
    int l16 = lane & 15;  // features 4*l16 .. 4*l16+3
    int v = blockIdx.x * WPB + (t >> 6);
    if (v >= N) return;
    int beg = offsets[v];
    int deg = cnt[v];
    float a0 = 0.f, a1 = 0.f, a2 = 0.f, a3 = 0.f;
    for (int j = 0; j < deg; j += 4) {
        int e = j + q;
        int s = (e < deg) ? csrc[beg + e] : -1;
        if (s >= 0) {
            uint2 d = H[(size_t)s * 16 + l16];
            a0 += bf16_lo(d.x); a1 += bf16_hi(d.x);
            a2 += bf16_lo(d.y); a3 += bf16_hi(d.y);
        }
    }
    a0 += __shfl_xor(a0, 16); a0 += __shfl_xor(a0, 32);
    a1 += __shfl_xor(a1, 16); a1 += __shfl_xor(a1, 32);
    a2 += __shfl_xor(a2, 16); a2 += __shfl_xor(a2, 32);
    a3 += __shfl_xor(a3, 16); a3 += __shfl_xor(a3, 32);
    if (lane < 16) {
        int f = l16 * 4;
        float dv = dinv[v];
        float r0 = fmaf(dv, a0, bias[f + 0]);
        float r1 = fmaf(dv, a1, bias[f + 1]);
        float r2 = fmaf(dv, a2, bias[f + 2]);
        float r3 = fmaf(dv, a3, bias[f + 3]);
        if (RELU_BF16OUT) {
            r0 = fmaxf(r0, 0.f); r1 = fmaxf(r1, 0.f);
            r2 = fmaxf(r2, 0.f); r3 = fmaxf(r3, 0.f);
            uint2 pk;
            pk.x = bf16_rne(r0) | (bf16_rne(r1) << 16);
            pk.y = bf16_rne(r2) | (bf16_rne(r3) << 16);
            ((uint2*)outv)[(size_t)v * 16 + l16] = pk;
        } else {
            float4 o = make_float4(r0, r1, r2, r3);
            ((float4*)outv)[(size_t)v * 16 + l16] = o;
        }
    }
}

extern "C" void kernel_launch(void* const* d_in, const int* in_sizes, int n_in,
                              void* d_out, int out_size, void* d_ws, size_t ws_size,
                              hipStream_t stream) {
    const float* x  = (const float*)d_in[0];
    const int*   ei = (const int*)d_in[1];  // harness delivers int32
    const float* W1 = (const float*)d_in[2];
    const float* b1 = (const float*)d_in[3];
    const float* W2 = (const float*)d_in[4];
    const float* b2 = (const float*)d_in[5];
    float* out      = (float*)d_out;

    const int N = in_sizes[0] / 64;
    const int E = in_sizes[1] / 2;
    const int* row = ei;
    const int* col = ei + E;
    const int T = E + N;
    const int NB = (N + BSZ - 1) >> BSH;  // buckets

    char* p = (char*)d_ws;
    auto alloc = [&](size_t bytes) { void* r = (void*)p; p += (bytes + 255) & ~(size_t)255; return r; };
    int*      bcnt    = (int*)alloc((size_t)(NB + 1) * 4);
    int*      boff    = (int*)alloc((size_t)(NB + 1) * 4);
    int*      bcur    = (int*)alloc((size_t)(NB + 1) * 4);
    int*      offsets = (int*)alloc((size_t)N * 4);
    int*      cnt     = (int*)alloc((size_t)N * 4);
    float*    dinv    = (float*)alloc((size_t)N * 4);
    unsigned* pairs   = (unsigned*)alloc((size_t)T * 4);
    int*      csrc    = (int*)alloc((size_t)T * 4);
    unsigned* hbuf    = (unsigned*)alloc((size_t)N * 32 * 4);  // bf16 packed
    unsigned* abuf    = (unsigned*)alloc((size_t)N * 32 * 4);  // bf16 packed

    k_binit<<<(NB + 511) / 512, 512, 0, stream>>>(bcnt, NB, N);
    k_bcount<<<512, 256, 0, stream>>>(col, E, bcnt, NB);
    k_bscan<<<1, 512, 0, stream>>>(bcnt, NB, boff, bcur);
    k_part<<<2048, 256, 0, stream>>>(row, col, E, N, bcur, pairs);
    k_bfill<<<NB, 256, 0, stream>>>(pairs, boff, N, offsets, cnt, dinv, csrc);

    const int GEMM_BLOCKS = 1024;
    const int GEMM_WAVES  = GEMM_BLOCKS * WPB;
    const int GB = (N + WPB - 1) / WPB;

    k_gemm<false><<<GEMM_BLOCKS, 256, 0, stream>>>(x, W1, dinv, hbuf, N, GEMM_WAVES);
    k_agg<true><<<GB, 256, 0, stream>>>((const uint2*)hbuf, offsets, cnt, csrc, dinv, b1, abuf, N);
    k_gemm<true><<<GEMM_BLOCKS, 256, 0, stream>>>(abuf, W2, dinv, hbuf, N, GEMM_WAVES);
    k_agg<false><<<GB, 256, 0, stream>>>((const uint2*)hbuf, offsets, cnt, csrc, dinv, b2, out, N);
}

// Round 5
// 430.689 us; speedup vs baseline: 2.5218x; 2.5218x over previous
//
#include <hip/hip_runtime.h>

// ---------------------------------------------------------------------------
// GCN 2-layer forward, round 5.
// CSR build = 2-level bucketed counting sort (256 nodes/bucket), with the
// partition done as a BLOCK-STAGED radix scatter (round-4 post-mortem: a
// per-edge global atomic on 391 bucket cursors serialized at ~150ns/op ->
// 678us. Now: LDS histogram per 4096-msg tile + ONE global atomic per
// (block,bucket) reservation + LDS-cursor ranked scatter).
//   k_binit  : bcnt[b] = #nodes in bucket (self loops pre-counted)
//   k_bcount : LDS histogram of edge destinations by bucket -> bcnt
//   k_bscan  : exclusive scan of bucket counts -> boff, bcur
//   k_part   : block-staged scatter of packed (src | (col&255)<<24)
//   k_bfill  : block per bucket: node histogram + scan -> offsets/cnt/dinv,
//              LDS-cursor fill of csrc
// Features packed bf16; norm folded into GEMM/agg epilogues.
// Requires N < 2^24 (src packed in 24 bits): N=100000 ok.
// ---------------------------------------------------------------------------

#define WPB 4      // waves per block (gemm/agg)
#define BSH 8      // bucket shift: 256 nodes per bucket
#define BSZ 256
#define PTILE 4096 // messages per partition tile

__device__ __forceinline__ unsigned bf16_rne(float f) {
    unsigned b = __float_as_uint(f);
    return (b + 0x7fffu + ((b >> 16) & 1u)) >> 16;
}
__device__ __forceinline__ float bf16_lo(unsigned u) { return __uint_as_float(u << 16); }
__device__ __forceinline__ float bf16_hi(unsigned u) { return __uint_as_float(u & 0xffff0000u); }

__global__ void k_binit(int* __restrict__ bcnt, int NB, int N) {
    int b = blockIdx.x * blockDim.x + threadIdx.x;
    if (b < NB) {
        int lo = b << BSH;
        int hi = min(N, lo + BSZ);
        bcnt[b] = hi - lo;  // self loops pre-counted
    }
}

__global__ __launch_bounds__(256) void k_bcount(const int* __restrict__ col, int E,
                                                int* __restrict__ bcnt, int NB) {
    __shared__ int hist[512];
    int t = threadIdx.x;
    for (int i = t; i < NB; i += 256) hist[i] = 0;
    __syncthreads();
    int i = blockIdx.x * blockDim.x + t;
    int stride = gridDim.x * blockDim.x;
    for (; i < E; i += stride) {
        atomicAdd(&hist[col[i] >> BSH], 1);
    }
    __syncthreads();
    for (int b = t; b < NB; b += 256) {
        int h = hist[b];
        if (h) atomicAdd(&bcnt[b], h);
    }
}

// Single block: exclusive scan of NB (<=512) bucket counts.
__global__ void k_bscan(const int* __restrict__ bcnt, int NB,
                        int* __restrict__ boff, int* __restrict__ bcur) {
    __shared__ int sh[513];
    int t = threadIdx.x;
    for (int i = t; i < NB; i += blockDim.x) sh[i] = bcnt[i];
    __syncthreads();
    if (t == 0) {
        int run = 0;
        for (int i = 0; i < NB; i++) { int v = sh[i]; sh[i] = run; run += v; }
        sh[NB] = run;
    }
    __syncthreads();
    for (int i = t; i <= NB; i += blockDim.x) boff[i] = sh[i];
    for (int i = t; i < NB; i += blockDim.x) bcur[i] = sh[i];
}

// Block-staged partition: one tile of PTILE messages per block iteration.
// Global atomics: one per (tile,bucket) with distinct addresses -> pipelined.
__global__ __launch_bounds__(256) void k_part(const int* __restrict__ rowi,
                                              const int* __restrict__ coli,
                                              int E, int N, int NB, int numTiles,
                                              int* __restrict__ bcur,
                                              unsigned* __restrict__ pairs) {
    __shared__ int hist[512];
    __shared__ int base[512];
    int t = threadIdx.x;
    int T = E + N;
    for (int tile = blockIdx.x; tile < numTiles; tile += gridDim.x) {
        int tstart = tile * PTILE;
        int m = min(PTILE, T - tstart);
        // phase 1: LDS histogram of this tile
        for (int b = t; b < NB; b += 256) hist[b] = 0;
        __syncthreads();
        for (int i = t; i < m; i += 256) {
            int g = tstart + i;
            int c = (g < E) ? coli[g] : (g - E);
            atomicAdd(&hist[c >> BSH], 1);
        }
        __syncthreads();
        // phase 2: reserve contiguous range per bucket (1 global atomic each)
        for (int b = t; b < NB; b += 256) {
            int h = hist[b];
            base[b] = h ? atomicAdd(&bcur[b], h) : 0;
            hist[b] = 0;  // reuse as local cursor
        }
        __syncthreads();
        // phase 3: ranked scatter (edges re-read; L2-hot)
        for (int i = t; i < m; i += 256) {
            int g = tstart + i;
            int r, c;
            if (g < E) { r = rowi[g]; c = coli[g]; }
            else       { r = g - E; c = r; }  // self loop
            int b = c >> BSH;
            int rank = atomicAdd(&hist[b], 1);
            pairs[base[b] + rank] = (unsigned)r | ((unsigned)(c & (BSZ - 1)) << 24);
        }
        __syncthreads();  // protect hist/base before next tile
    }
}

// One block per bucket: histogram its <=256 nodes, scan, emit CSR meta, fill csrc.
__global__ __launch_bounds__(256) void k_bfill(const unsigned* __restrict__ pairs,
                                               const int* __restrict__ boff,
                                               int N,
                                               int* __restrict__ offsets,
                                               int* __restrict__ cnt,
                                               float* __restrict__ dinv,
                                               int* __restrict__ csrc) {
    __shared__ int scnt[BSZ];
    __shared__ int scur[BSZ];
    __shared__ int wsum[4];
    int b = blockIdx.x;
    int t = threadIdx.x;
    int ebeg = boff[b];
    int m = boff[b + 1] - ebeg;
    scnt[t] = 0;
    __syncthreads();
    for (int i = t; i < m; i += 256) {
        atomicAdd(&scnt[pairs[ebeg + i] >> 24], 1);
    }
    __syncthreads();
    int cval = scnt[t];
    int lane = t & 63, wid = t >> 6;
    int inc = cval;
    #pragma unroll
    for (int d = 1; d < 64; d <<= 1) {
        int o = __shfl_up(inc, d);
        if (lane >= d) inc += o;
    }
    if (lane == 63) wsum[wid] = inc;
    __syncthreads();
    int woff = 0;
    for (int i = 0; i < wid; i++) woff += wsum[i];
    int off = ebeg + woff + inc - cval;  // CSR offset for node (b<<BSH)+t
    int v = (b << BSH) + t;
    if (v < N) {
        offsets[v] = off;
        cnt[v] = cval;
        dinv[v] = rsqrtf((float)cval);  // cval >= 1 (self loop)
    }
    scur[t] = off;
    __syncthreads();
    for (int i = t; i < m; i += 256) {
        unsigned pk = pairs[ebeg + i];
        int slot = atomicAdd(&scur[pk >> 24], 1);
        csrc[slot] = (int)(pk & 0xFFFFFFu);
    }
}

// H[row] = dinv[row] * (X[row] @ W), output packed bf16 (32 uints/row).
template <bool BF16IN>
__global__ __launch_bounds__(256) void k_gemm(const void* __restrict__ Xv,
                                              const float* __restrict__ W,
                                              const float* __restrict__ dinv,
                                              unsigned* __restrict__ Hout,
                                              int N, int totalWaves) {
    __shared__ float Ws[64 * 64];
    int t = threadIdx.x;
    {
        const float4* W4 = (const float4*)W;
        float4* Ws4 = (float4*)Ws;
        for (int i = t; i < 1024; i += 256) Ws4[i] = W4[i];
    }
    __syncthreads();
    int lane = t & 63;
    int wave = blockIdx.x * WPB + (t >> 6);
    for (int row = wave; row < N; row += totalWaves) {
        float f0, f1 = 0.f;
        if (BF16IN) {
            const unsigned* A = (const unsigned*)Xv;
            unsigned u = A[(size_t)row * 32 + (lane & 31)];
            f0 = bf16_lo(u); f1 = bf16_hi(u);
        } else {
            const float* X = (const float*)Xv;
            f0 = X[(size_t)row * 64 + lane];
        }
        float acc = 0.f;
        #pragma unroll
        for (int k = 0; k < 64; k++) {
            float xk = BF16IN ? __shfl((k & 1) ? f1 : f0, k >> 1)
                              : __shfl(f0, k);
            acc = fmaf(xk, Ws[k * 64 + lane], acc);
        }
        float val = acc * dinv[row];
        float p0 = __shfl(val, (lane & 31) * 2);
        float p1 = __shfl(val, (lane & 31) * 2 + 1);
        if (lane < 32) {
            Hout[(size_t)row * 32 + lane] = bf16_rne(p0) | (bf16_rne(p1) << 16);
        }
    }
}

// out[v] = epi( dinv[v] * sum_{j in CSR[v]} H[src_j] + bias )
template <bool RELU_BF16OUT>
__global__ __launch_bounds__(256) void k_agg(const uint2* __restrict__ H,
                                             const int* __restrict__ offsets,
                                             const int* __restrict__ cnt,
                                             const int* __restrict__ csrc,
                                             const float* __restrict__ dinv,
                                             const float* __restrict__ bias,
                                             void* __restrict__ outv, int N) {
    int t = threadIdx.x;
    int lane = t & 63;
    int q = lane >> 4;    // quarter 0..3 -> edge j+q
    int l16 = lane & 15;  // features 4*l16 .. 4*l16+3
    int v = blockIdx.x * WPB + (t >> 6);
    if (v >= N) return;
    int beg = offsets[v];
    int deg = cnt[v];
    float a0 = 0.f, a1 = 0.f, a2 = 0.f, a3 = 0.f;
    for (int j = 0; j < deg; j += 4) {
        int e = j + q;
        int s = (e < deg) ? csrc[beg + e] : -1;
        if (s >= 0) {
            uint2 d = H[(size_t)s * 16 + l16];
            a0 += bf16_lo(d.x); a1 += bf16_hi(d.x);
            a2 += bf16_lo(d.y); a3 += bf16_hi(d.y);
        }
    }
    a0 += __shfl_xor(a0, 16); a0 += __shfl_xor(a0, 32);
    a1 += __shfl_xor(a1, 16); a1 += __shfl_xor(a1, 32);
    a2 += __shfl_xor(a2, 16); a2 += __shfl_xor(a2, 32);
    a3 += __shfl_xor(a3, 16); a3 += __shfl_xor(a3, 32);
    if (lane < 16) {
        int f = l16 * 4;
        float dv = dinv[v];
        float r0 = fmaf(dv, a0, bias[f + 0]);
        float r1 = fmaf(dv, a1, bias[f + 1]);
        float r2 = fmaf(dv, a2, bias[f + 2]);
        float r3 = fmaf(dv, a3, bias[f + 3]);
        if (RELU_BF16OUT) {
            r0 = fmaxf(r0, 0.f); r1 = fmaxf(r1, 0.f);
            r2 = fmaxf(r2, 0.f); r3 = fmaxf(r3, 0.f);
            uint2 pk;
            pk.x = bf16_rne(r0) | (bf16_rne(r1) << 16);
            pk.y = bf16_rne(r2) | (bf16_rne(r3) << 16);
            ((uint2*)outv)[(size_t)v * 16 + l16] = pk;
        } else {
            float4 o = make_float4(r0, r1, r2, r3);
            ((float4*)outv)[(size_t)v * 16 + l16] = o;
        }
    }
}

extern "C" void kernel_launch(void* const* d_in, const int* in_sizes, int n_in,
                              void* d_out, int out_size, void* d_ws, size_t ws_size,
                              hipStream_t stream) {
    const float* x  = (const float*)d_in[0];
    const int*   ei = (const int*)d_in[1];  // harness delivers int32
    const float* W1 = (const float*)d_in[2];
    const float* b1 = (const float*)d_in[3];
    const float* W2 = (const float*)d_in[4];
    const float* b2 = (const float*)d_in[5];
    float* out      = (float*)d_out;

    const int N = in_sizes[0] / 64;
    const int E = in_sizes[1] / 2;
    const int* row = ei;
    const int* col = ei + E;
    const int T = E + N;
    const int NB = (N + BSZ - 1) >> BSH;  // buckets

    char* p = (char*)d_ws;
    auto alloc = [&](size_t bytes) { void* r = (void*)p; p += (bytes + 255) & ~(size_t)255; return r; };
    int*      bcnt    = (int*)alloc((size_t)(NB + 1) * 4);
    int*      boff    = (int*)alloc((size_t)(NB + 1) * 4);
    int*      bcur    = (int*)alloc((size_t)(NB + 1) * 4);
    int*      offsets = (int*)alloc((size_t)N * 4);
    int*      cnt     = (int*)alloc((size_t)N * 4);
    float*    dinv    = (float*)alloc((size_t)N * 4);
    unsigned* pairs   = (unsigned*)alloc((size_t)T * 4);
    int*      csrc    = (int*)alloc((size_t)T * 4);
    unsigned* hbuf    = (unsigned*)alloc((size_t)N * 32 * 4);  // bf16 packed
    unsigned* abuf    = (unsigned*)alloc((size_t)N * 32 * 4);  // bf16 packed

    const int numTiles = (T + PTILE - 1) / PTILE;

    k_binit<<<(NB + 511) / 512, 512, 0, stream>>>(bcnt, NB, N);
    k_bcount<<<512, 256, 0, stream>>>(col, E, bcnt, NB);
    k_bscan<<<1, 512, 0, stream>>>(bcnt, NB, boff, bcur);
    k_part<<<numTiles, 256, 0, stream>>>(row, col, E, N, NB, numTiles, bcur, pairs);
    k_bfill<<<NB, 256, 0, stream>>>(pairs, boff, N, offsets, cnt, dinv, csrc);

    const int GEMM_BLOCKS = 1024;
    const int GEMM_WAVES  = GEMM_BLOCKS * WPB;
    const int GB = (N + WPB - 1) / WPB;

    k_gemm<false><<<GEMM_BLOCKS, 256, 0, stream>>>(x, W1, dinv, hbuf, N, GEMM_WAVES);
    k_agg<true><<<GB, 256, 0, stream>>>((const uint2*)hbuf, offsets, cnt, csrc, dinv, b1, abuf, N);
    k_gemm<true><<<GEMM_BLOCKS, 256, 0, stream>>>(abuf, W2, dinv, hbuf, N, GEMM_WAVES);
    k_agg<false><<<GB, 256, 0, stream>>>((const uint2*)hbuf, offsets, cnt, csrc, dinv, b2, out, N);
}

// Round 6
// 301.376 us; speedup vs baseline: 3.6039x; 1.4291x over previous
//
#include <hip/hip_runtime.h>

// ---------------------------------------------------------------------------
// GCN 2-layer forward, round 6.
// Round-5 post-mortem: shfl-based scalar GEMM was VALU-latency-bound (83us,
// VALUBusy 22%, 400k LDS conflicts). Replaced with MFMA 16x16x32 bf16:
//   - wave per 16-row slab; W held in registers as 8 B-fragments
//     (2 k-tiles x 4 col-tiles), staged once through LDS;
//   - A-frag: lane (m=lane&15, kq=lane>>4) loads 8 consecutive bf16 (uint4);
//   - 8 MFMAs/slab; epilogue scales by dinv[row], transposes via LDS
//     (66-float pitch), stores packed-bf16 rows as uint4.
// CSR build (bucketed counting sort + block-staged partition) and the
// gather-aggregate are unchanged from round 5.
// ---------------------------------------------------------------------------

#define WPB 4      // waves per block (agg)
#define BSH 8      // bucket shift: 256 nodes per bucket
#define BSZ 256
#define PTILE 4096 // messages per partition tile

typedef __attribute__((ext_vector_type(8))) short bf16x8;
typedef __attribute__((ext_vector_type(4))) float f32x4;

__device__ __forceinline__ unsigned bf16_rne(float f) {
    unsigned b = __float_as_uint(f);
    return (b + 0x7fffu + ((b >> 16) & 1u)) >> 16;
}
__device__ __forceinline__ float bf16_lo(unsigned u) { return __uint_as_float(u << 16); }
__device__ __forceinline__ float bf16_hi(unsigned u) { return __uint_as_float(u & 0xffff0000u); }

__global__ void k_binit(int* __restrict__ bcnt, int NB, int N) {
    int b = blockIdx.x * blockDim.x + threadIdx.x;
    if (b < NB) {
        int lo = b << BSH;
        int hi = min(N, lo + BSZ);
        bcnt[b] = hi - lo;  // self loops pre-counted
    }
}

__global__ __launch_bounds__(256) void k_bcount(const int* __restrict__ col, int E,
                                                int* __restrict__ bcnt, int NB) {
    __shared__ int hist[512];
    int t = threadIdx.x;
    for (int i = t; i < NB; i += 256) hist[i] = 0;
    __syncthreads();
    int i = blockIdx.x * blockDim.x + t;
    int stride = gridDim.x * blockDim.x;
    for (; i < E; i += stride) {
        atomicAdd(&hist[col[i] >> BSH], 1);
    }
    __syncthreads();
    for (int b = t; b < NB; b += 256) {
        int h = hist[b];
        if (h) atomicAdd(&bcnt[b], h);
    }
}

// Single block: exclusive scan of NB (<=512) bucket counts.
__global__ void k_bscan(const int* __restrict__ bcnt, int NB,
                        int* __restrict__ boff, int* __restrict__ bcur) {
    __shared__ int sh[513];
    int t = threadIdx.x;
    for (int i = t; i < NB; i += blockDim.x) sh[i] = bcnt[i];
    __syncthreads();
    if (t == 0) {
        int run = 0;
        for (int i = 0; i < NB; i++) { int v = sh[i]; sh[i] = run; run += v; }
        sh[NB] = run;
    }
    __syncthreads();
    for (int i = t; i <= NB; i += blockDim.x) boff[i] = sh[i];
    for (int i = t; i < NB; i += blockDim.x) bcur[i] = sh[i];
}

// Block-staged partition: one tile of PTILE messages per block iteration.
__global__ __launch_bounds__(256) void k_part(const int* __restrict__ rowi,
                                              const int* __restrict__ coli,
                                              int E, int N, int NB, int numTiles,
                                              int* __restrict__ bcur,
                                              unsigned* __restrict__ pairs) {
    __shared__ int hist[512];
    __shared__ int base[512];
    int t = threadIdx.x;
    int T = E + N;
    for (int tile = blockIdx.x; tile < numTiles; tile += gridDim.x) {
        int tstart = tile * PTILE;
        int m = min(PTILE, T - tstart);
        for (int b = t; b < NB; b += 256) hist[b] = 0;
        __syncthreads();
        for (int i = t; i < m; i += 256) {
            int g = tstart + i;
            int c = (g < E) ? coli[g] : (g - E);
            atomicAdd(&hist[c >> BSH], 1);
        }
        __syncthreads();
        for (int b = t; b < NB; b += 256) {
            int h = hist[b];
            base[b] = h ? atomicAdd(&bcur[b], h) : 0;
            hist[b] = 0;  // reuse as local cursor
        }
        __syncthreads();
        for (int i = t; i < m; i += 256) {
            int g = tstart + i;
            int r, c;
            if (g < E) { r = rowi[g]; c = coli[g]; }
            else       { r = g - E; c = r; }  // self loop
            int b = c >> BSH;
            int rank = atomicAdd(&hist[b], 1);
            pairs[base[b] + rank] = (unsigned)r | ((unsigned)(c & (BSZ - 1)) << 24);
        }
        __syncthreads();
    }
}

// One block per bucket: histogram its <=256 nodes, scan, emit CSR meta, fill csrc.
__global__ __launch_bounds__(256) void k_bfill(const unsigned* __restrict__ pairs,
                                               const int* __restrict__ boff,
                                               int N,
                                               int* __restrict__ offsets,
                                               int* __restrict__ cnt,
                                               float* __restrict__ dinv,
                                               int* __restrict__ csrc) {
    __shared__ int scnt[BSZ];
    __shared__ int scur[BSZ];
    __shared__ int wsum[4];
    int b = blockIdx.x;
    int t = threadIdx.x;
    int ebeg = boff[b];
    int m = boff[b + 1] - ebeg;
    scnt[t] = 0;
    __syncthreads();
    for (int i = t; i < m; i += 256) {
        atomicAdd(&scnt[pairs[ebeg + i] >> 24], 1);
    }
    __syncthreads();
    int cval = scnt[t];
    int lane = t & 63, wid = t >> 6;
    int inc = cval;
    #pragma unroll
    for (int d = 1; d < 64; d <<= 1) {
        int o = __shfl_up(inc, d);
        if (lane >= d) inc += o;
    }
    if (lane == 63) wsum[wid] = inc;
    __syncthreads();
    int woff = 0;
    for (int i = 0; i < wid; i++) woff += wsum[i];
    int off = ebeg + woff + inc - cval;  // CSR offset for node (b<<BSH)+t
    int v = (b << BSH) + t;
    if (v < N) {
        offsets[v] = off;
        cnt[v] = cval;
        dinv[v] = rsqrtf((float)cval);  // cval >= 1 (self loop)
    }
    scur[t] = off;
    __syncthreads();
    for (int i = t; i < m; i += 256) {
        unsigned pk = pairs[ebeg + i];
        int slot = atomicAdd(&scur[pk >> 24], 1);
        csrc[slot] = (int)(pk & 0xFFFFFFu);
    }
}

// H[row] = dinv[row] * (X[row] @ W) via mfma_f32_16x16x32_bf16.
// Layouts (verified, learn_hip m89/m120): A[m=lane&15][k=(lane>>4)*8+j],
// B[k=(lane>>4)*8+j][n=lane&15], C: col=lane&15, row=(lane>>4)*4+reg.
template <bool BF16IN>
__global__ __launch_bounds__(256) void k_gemm(const void* __restrict__ Xv,
                                              const float* __restrict__ W,
                                              const float* __restrict__ dinv,
                                              unsigned* __restrict__ Hout,
                                              int N, int nSlabs, int slabStride) {
    __shared__ float SMEM[4224];  // 4096 for W staging, then 4 x (16x66) transpose
    int t = threadIdx.x;
    int lane = t & 63, w = t >> 6;
    int nn = lane & 15, kq = lane >> 4;

    // stage W (fp32) coalesced, then pull B-fragments into registers
    for (int i = t; i < 1024; i += 256) ((float4*)SMEM)[i] = ((const float4*)W)[i];
    __syncthreads();
    bf16x8 Bf[2][4];
    #pragma unroll
    for (int kt = 0; kt < 2; kt++) {
        #pragma unroll
        for (int ct = 0; ct < 4; ct++) {
            union { bf16x8 v; unsigned short s[8]; } u;
            #pragma unroll
            for (int j = 0; j < 8; j++) {
                int k = kt * 32 + kq * 8 + j;
                u.s[j] = (unsigned short)bf16_rne(SMEM[k * 64 + ct * 16 + nn]);
            }
            Bf[kt][ct] = u.v;
        }
    }
    __syncthreads();  // W region now dead; SMEM becomes transpose scratch

    float* outT = SMEM + w * 1056;  // 16 rows x 66 floats

    for (int slab = blockIdx.x * 4 + w; slab < nSlabs; slab += slabStride) {
        int row0 = slab * 16;
        int rowA = min(row0 + nn, N - 1);
        // A fragments
        bf16x8 A0, A1;
        if (BF16IN) {
            const uint4* X = (const uint4*)Xv;  // row = 8 uint4
            union { uint4 u; bf16x8 v; } a0, a1;
            a0.u = X[(size_t)rowA * 8 + kq];
            a1.u = X[(size_t)rowA * 8 + 4 + kq];
            A0 = a0.v; A1 = a1.v;
        } else {
            const float4* X = (const float4*)Xv;  // row = 16 float4
            float4 f0 = X[(size_t)rowA * 16 + kq * 2];
            float4 f1 = X[(size_t)rowA * 16 + kq * 2 + 1];
            float4 f2 = X[(size_t)rowA * 16 + 8 + kq * 2];
            float4 f3 = X[(size_t)rowA * 16 + 8 + kq * 2 + 1];
            union { bf16x8 v; unsigned short s[8]; } a0, a1;
            a0.s[0] = (unsigned short)bf16_rne(f0.x); a0.s[1] = (unsigned short)bf16_rne(f0.y);
            a0.s[2] = (unsigned short)bf16_rne(f0.z); a0.s[3] = (unsigned short)bf16_rne(f0.w);
            a0.s[4] = (unsigned short)bf16_rne(f1.x); a0.s[5] = (unsigned short)bf16_rne(f1.y);
            a0.s[6] = (unsigned short)bf16_rne(f1.z); a0.s[7] = (unsigned short)bf16_rne(f1.w);
            a1.s[0] = (unsigned short)bf16_rne(f2.x); a1.s[1] = (unsigned short)bf16_rne(f2.y);
            a1.s[2] = (unsigned short)bf16_rne(f2.z); a1.s[3] = (unsigned short)bf16_rne(f2.w);
            a1.s[4] = (unsigned short)bf16_rne(f3.x); a1.s[5] = (unsigned short)bf16_rne(f3.y);
            a1.s[6] = (unsigned short)bf16_rne(f3.z); a1.s[7] = (unsigned short)bf16_rne(f3.w);
            A0 = a0.v; A1 = a1.v;
        }
        float dvm = dinv[rowA];

        f32x4 acc[4];
        #pragma unroll
        for (int ct = 0; ct < 4; ct++) acc[ct] = (f32x4){0.f, 0.f, 0.f, 0.f};
        #pragma unroll
        for (int ct = 0; ct < 4; ct++) {
            acc[ct] = __builtin_amdgcn_mfma_f32_16x16x32_bf16(A0, Bf[0][ct], acc[ct], 0, 0, 0);
            acc[ct] = __builtin_amdgcn_mfma_f32_16x16x32_bf16(A1, Bf[1][ct], acc[ct], 0, 0, 0);
        }

        // epilogue: scale rows by dinv, transpose via LDS, store packed bf16
        #pragma unroll
        for (int reg = 0; reg < 4; reg++) {
            int r = kq * 4 + reg;
            float dv = __shfl(dvm, r);  // lane r holds dinv[row0+r]
            #pragma unroll
            for (int ct = 0; ct < 4; ct++) {
                outT[r * 66 + ct * 16 + nn] = acc[ct][reg] * dv;
            }
        }
        // wave-synchronous readback (no barrier needed: own region only)
        int rr = lane >> 2;        // 4 lanes per row
        int c0 = (lane & 3) * 16;  // 16 cols per lane
        int orow = row0 + rr;
        if (orow < N) {
            unsigned pk[8];
            #pragma unroll
            for (int i = 0; i < 8; i++) {
                float lo = outT[rr * 66 + c0 + 2 * i];
                float hi = outT[rr * 66 + c0 + 2 * i + 1];
                pk[i] = bf16_rne(lo) | (bf16_rne(hi) << 16);
            }
            uint4* dst = (uint4*)Hout + (size_t)orow * 8 + (lane & 3) * 2;
            dst[0] = make_uint4(pk[0], pk[1], pk[2], pk[3]);
            dst[1] = make_uint4(pk[4], pk[5], pk[6], pk[7]);
        }
    }
}

// out[v] = epi( dinv[v] * sum_{j in CSR[v]} H[src_j] + bias )
template <bool RELU_BF16OUT>
__global__ __launch_bounds__(256) void k_agg(const uint2* __restrict__ H,
                                             const int* __restrict__ offsets,
                                             const int* __restrict__ cnt,
                                             const int* __restrict__ csrc,
                                             const float* __restrict__ dinv,
                                             const float* __restrict__ bias,
                                             void* __restrict__ outv, int N) {
    int t = threadIdx.x;
    int lane = t & 63;
    int q = lane >> 4;    // quarter 0..3 -> edge j+q
    int l16 = lane & 15;  // features 4*l16 .. 4*l16+3
    int v = blockIdx.x * WPB + (t >> 6);
    if (v >= N) return;
    int beg = offsets[v];
    int deg = cnt[v];
    float a0 = 0.f, a1 = 0.f, a2 = 0.f, a3 = 0.f;
    for (int j = 0; j < deg; j += 4) {
        int e = j + q;
        int s = (e < deg) ? csrc[beg + e] : -1;
        if (s >= 0) {
            uint2 d = H[(size_t)s * 16 + l16];
            a0 += bf16_lo(d.x); a1 += bf16_hi(d.x);
            a2 += bf16_lo(d.y); a3 += bf16_hi(d.y);
        }
    }
    a0 += __shfl_xor(a0, 16); a0 += __shfl_xor(a0, 32);
    a1 += __shfl_xor(a1, 16); a1 += __shfl_xor(a1, 32);
    a2 += __shfl_xor(a2, 16); a2 += __shfl_xor(a2, 32);
    a3 += __shfl_xor(a3, 16); a3 += __shfl_xor(a3, 32);
    if (lane < 16) {
        int f = l16 * 4;
        float dv = dinv[v];
        float r0 = fmaf(dv, a0, bias[f + 0]);
        float r1 = fmaf(dv, a1, bias[f + 1]);
        float r2 = fmaf(dv, a2, bias[f + 2]);
        float r3 = fmaf(dv, a3, bias[f + 3]);
        if (RELU_BF16OUT) {
            r0 = fmaxf(r0, 0.f); r1 = fmaxf(r1, 0.f);
            r2 = fmaxf(r2, 0.f); r3 = fmaxf(r3, 0.f);
            uint2 pk;
            pk.x = bf16_rne(r0) | (bf16_rne(r1) << 16);
            pk.y = bf16_rne(r2) | (bf16_rne(r3) << 16);
            ((uint2*)outv)[(size_t)v * 16 + l16] = pk;
        } else {
            float4 o = make_float4(r0, r1, r2, r3);
            ((float4*)outv)[(size_t)v * 16 + l16] = o;
        }
    }
}

extern "C" void kernel_launch(void* const* d_in, const int* in_sizes, int n_in,
                              void* d_out, int out_size, void* d_ws, size_t ws_size,
                              hipStream_t stream) {
    const float* x  = (const float*)d_in[0];
    const int*   ei = (const int*)d_in[1];  // harness delivers int32
    const float* W1 = (const float*)d_in[2];
    const float* b1 = (const float*)d_in[3];
    const float* W2 = (const float*)d_in[4];
    const float* b2 = (const float*)d_in[5];
    float* out      = (float*)d_out;

    const int N = in_sizes[0] / 64;
    const int E = in_sizes[1] / 2;
    const int* row = ei;
    const int* col = ei + E;
    const int T = E + N;
    const int NB = (N + BSZ - 1) >> BSH;  // buckets

    char* p = (char*)d_ws;
    auto alloc = [&](size_t bytes) { void* r = (void*)p; p += (bytes + 255) & ~(size_t)255; return r; };
    int*      bcnt    = (int*)alloc((size_t)(NB + 1) * 4);
    int*      boff    = (int*)alloc((size_t)(NB + 1) * 4);
    int*      bcur    = (int*)alloc((size_t)(NB + 1) * 4);
    int*      offsets = (int*)alloc((size_t)N * 4);
    int*      cnt     = (int*)alloc((size_t)N * 4);
    float*    dinv    = (float*)alloc((size_t)N * 4);
    unsigned* pairs   = (unsigned*)alloc((size_t)T * 4);
    int*      csrc    = (int*)alloc((size_t)T * 4);
    unsigned* hbuf    = (unsigned*)alloc((size_t)N * 32 * 4);  // bf16 packed
    unsigned* abuf    = (unsigned*)alloc((size_t)N * 32 * 4);  // bf16 packed

    const int numTiles = (T + PTILE - 1) / PTILE;

    k_binit<<<(NB + 511) / 512, 512, 0, stream>>>(bcnt, NB, N);
    k_bcount<<<512, 256, 0, stream>>>(col, E, bcnt, NB);
    k_bscan<<<1, 512, 0, stream>>>(bcnt, NB, boff, bcur);
    k_part<<<numTiles, 256, 0, stream>>>(row, col, E, N, NB, numTiles, bcur, pairs);
    k_bfill<<<NB, 256, 0, stream>>>(pairs, boff, N, offsets, cnt, dinv, csrc);

    const int nSlabs = (N + 15) / 16;
    const int GEMM_BLOCKS = 512;                 // 4 waves each
    const int SLAB_STRIDE = GEMM_BLOCKS * 4;
    const int GB = (N + WPB - 1) / WPB;

    k_gemm<false><<<GEMM_BLOCKS, 256, 0, stream>>>(x, W1, dinv, hbuf, N, nSlabs, SLAB_STRIDE);
    k_agg<true><<<GB, 256, 0, stream>>>((const uint2*)hbuf, offsets, cnt, csrc, dinv, b1, abuf, N);
    k_gemm<true><<<GEMM_BLOCKS, 256, 0, stream>>>(abuf, W2, dinv, hbuf, N, nSlabs, SLAB_STRIDE);
    k_agg<false><<<GB, 256, 0, stream>>>((const uint2*)hbuf, offsets, cnt, csrc, dinv, b2, out, N);
}

// Round 7
// 262.344 us; speedup vs baseline: 4.1401x; 1.1488x over previous
//
#include <hip/hip_runtime.h>

// ---------------------------------------------------------------------------
// GCN 2-layer forward, round 7.
// Round-6 post-mortem: k_agg (2x70us) is the top cost; VALUBusy 31% with only
// 4 edges per wave-iteration suggests issue/latency limits, not pure BW.
// Change (single variable): gather restructured to 8 lanes x uint4 per edge
// (8 edges per wave-wide load) + 2x unroll (16 edges in flight, dual
// accumulators). CSR build, MFMA GEMM unchanged from round 6.
// ---------------------------------------------------------------------------

#define WPB 4      // waves per block (agg)
#define BSH 8      // bucket shift: 256 nodes per bucket
#define BSZ 256
#define PTILE 4096 // messages per partition tile

typedef __attribute__((ext_vector_type(8))) short bf16x8;
typedef __attribute__((ext_vector_type(4))) float f32x4;

__device__ __forceinline__ unsigned bf16_rne(float f) {
    unsigned b = __float_as_uint(f);
    return (b + 0x7fffu + ((b >> 16) & 1u)) >> 16;
}
__device__ __forceinline__ float bf16_lo(unsigned u) { return __uint_as_float(u << 16); }
__device__ __forceinline__ float bf16_hi(unsigned u) { return __uint_as_float(u & 0xffff0000u); }

__global__ void k_binit(int* __restrict__ bcnt, int NB, int N) {
    int b = blockIdx.x * blockDim.x + threadIdx.x;
    if (b < NB) {
        int lo = b << BSH;
        int hi = min(N, lo + BSZ);
        bcnt[b] = hi - lo;  // self loops pre-counted
    }
}

__global__ __launch_bounds__(256) void k_bcount(const int* __restrict__ col, int E,
                                                int* __restrict__ bcnt, int NB) {
    __shared__ int hist[512];
    int t = threadIdx.x;
    for (int i = t; i < NB; i += 256) hist[i] = 0;
    __syncthreads();
    int i = blockIdx.x * blockDim.x + t;
    int stride = gridDim.x * blockDim.x;
    for (; i < E; i += stride) {
        atomicAdd(&hist[col[i] >> BSH], 1);
    }
    __syncthreads();
    for (int b = t; b < NB; b += 256) {
        int h = hist[b];
        if (h) atomicAdd(&bcnt[b], h);
    }
}

// Single block: exclusive scan of NB (<=512) bucket counts.
__global__ void k_bscan(const int* __restrict__ bcnt, int NB,
                        int* __restrict__ boff, int* __restrict__ bcur) {
    __shared__ int sh[513];
    int t = threadIdx.x;
    for (int i = t; i < NB; i += blockDim.x) sh[i] = bcnt[i];
    __syncthreads();
    if (t == 0) {
        int run = 0;
        for (int i = 0; i < NB; i++) { int v = sh[i]; sh[i] = run; run += v; }
        sh[NB] = run;
    }
    __syncthreads();
    for (int i = t; i <= NB; i += blockDim.x) boff[i] = sh[i];
    for (int i = t; i < NB; i += blockDim.x) bcur[i] = sh[i];
}

// Block-staged partition: one tile of PTILE messages per block iteration.
__global__ __launch_bounds__(256) void k_part(const int* __restrict__ rowi,
                                              const int* __restrict__ coli,
                                              int E, int N, int NB, int numTiles,
                                              int* __restrict__ bcur,
                                              unsigned* __restrict__ pairs) {
    __shared__ int hist[512];
    __shared__ int base[512];
    int t = threadIdx.x;
    int T = E + N;
    for (int tile = blockIdx.x; tile < numTiles; tile += gridDim.x) {
        int tstart = tile * PTILE;
        int m = min(PTILE, T - tstart);
        for (int b = t; b < NB; b += 256) hist[b] = 0;
        __syncthreads();
        for (int i = t; i < m; i += 256) {
            int g = tstart + i;
            int c = (g < E) ? coli[g] : (g - E);
            atomicAdd(&hist[c >> BSH], 1);
        }
        __syncthreads();
        for (int b = t; b < NB; b += 256) {
            int h = hist[b];
            base[b] = h ? atomicAdd(&bcur[b], h) : 0;
            hist[b] = 0;  // reuse as local cursor
        }
        __syncthreads();
        for (int i = t; i < m; i += 256) {
            int g = tstart + i;
            int r, c;
            if (g < E) { r = rowi[g]; c = coli[g]; }
            else       { r = g - E; c = r; }  // self loop
            int b = c >> BSH;
            int rank = atomicAdd(&hist[b], 1);
            pairs[base[b] + rank] = (unsigned)r | ((unsigned)(c & (BSZ - 1)) << 24);
        }
        __syncthreads();
    }
}

// One block per bucket: histogram its <=256 nodes, scan, emit CSR meta, fill csrc.
__global__ __launch_bounds__(256) void k_bfill(const unsigned* __restrict__ pairs,
                                               const int* __restrict__ boff,
                                               int N,
                                               int* __restrict__ offsets,
                                               int* __restrict__ cnt,
                                               float* __restrict__ dinv,
                                               int* __restrict__ csrc) {
    __shared__ int scnt[BSZ];
    __shared__ int scur[BSZ];
    __shared__ int wsum[4];
    int b = blockIdx.x;
    int t = threadIdx.x;
    int ebeg = boff[b];
    int m = boff[b + 1] - ebeg;
    scnt[t] = 0;
    __syncthreads();
    for (int i = t; i < m; i += 256) {
        atomicAdd(&scnt[pairs[ebeg + i] >> 24], 1);
    }
    __syncthreads();
    int cval = scnt[t];
    int lane = t & 63, wid = t >> 6;
    int inc = cval;
    #pragma unroll
    for (int d = 1; d < 64; d <<= 1) {
        int o = __shfl_up(inc, d);
        if (lane >= d) inc += o;
    }
    if (lane == 63) wsum[wid] = inc;
    __syncthreads();
    int woff = 0;
    for (int i = 0; i < wid; i++) woff += wsum[i];
    int off = ebeg + woff + inc - cval;  // CSR offset for node (b<<BSH)+t
    int v = (b << BSH) + t;
    if (v < N) {
        offsets[v] = off;
        cnt[v] = cval;
        dinv[v] = rsqrtf((float)cval);  // cval >= 1 (self loop)
    }
    scur[t] = off;
    __syncthreads();
    for (int i = t; i < m; i += 256) {
        unsigned pk = pairs[ebeg + i];
        int slot = atomicAdd(&scur[pk >> 24], 1);
        csrc[slot] = (int)(pk & 0xFFFFFFu);
    }
}

// H[row] = dinv[row] * (X[row] @ W) via mfma_f32_16x16x32_bf16.
template <bool BF16IN>
__global__ __launch_bounds__(256) void k_gemm(const void* __restrict__ Xv,
                                              const float* __restrict__ W,
                                              const float* __restrict__ dinv,
                                              unsigned* __restrict__ Hout,
                                              int N, int nSlabs, int slabStride) {
    __shared__ float SMEM[4224];  // 4096 for W staging, then 4 x (16x66) transpose
    int t = threadIdx.x;
    int lane = t & 63, w = t >> 6;
    int nn = lane & 15, kq = lane >> 4;

    for (int i = t; i < 1024; i += 256) ((float4*)SMEM)[i] = ((const float4*)W)[i];
    __syncthreads();
    bf16x8 Bf[2][4];
    #pragma unroll
    for (int kt = 0; kt < 2; kt++) {
        #pragma unroll
        for (int ct = 0; ct < 4; ct++) {
            union { bf16x8 v; unsigned short s[8]; } u;
            #pragma unroll
            for (int j = 0; j < 8; j++) {
                int k = kt * 32 + kq * 8 + j;
                u.s[j] = (unsigned short)bf16_rne(SMEM[k * 64 + ct * 16 + nn]);
            }
            Bf[kt][ct] = u.v;
        }
    }
    __syncthreads();  // W region dead; SMEM becomes transpose scratch

    float* outT = SMEM + w * 1056;  // 16 rows x 66 floats

    for (int slab = blockIdx.x * 4 + w; slab < nSlabs; slab += slabStride) {
        int row0 = slab * 16;
        int rowA = min(row0 + nn, N - 1);
        bf16x8 A0, A1;
        if (BF16IN) {
            const uint4* X = (const uint4*)Xv;  // row = 8 uint4
            union { uint4 u; bf16x8 v; } a0, a1;
            a0.u = X[(size_t)rowA * 8 + kq];
            a1.u = X[(size_t)rowA * 8 + 4 + kq];
            A0 = a0.v; A1 = a1.v;
        } else {
            const float4* X = (const float4*)Xv;  // row = 16 float4
            float4 f0 = X[(size_t)rowA * 16 + kq * 2];
            float4 f1 = X[(size_t)rowA * 16 + kq * 2 + 1];
            float4 f2 = X[(size_t)rowA * 16 + 8 + kq * 2];
            float4 f3 = X[(size_t)rowA * 16 + 8 + kq * 2 + 1];
            union { bf16x8 v; unsigned short s[8]; } a0, a1;
            a0.s[0] = (unsigned short)bf16_rne(f0.x); a0.s[1] = (unsigned short)bf16_rne(f0.y);
            a0.s[2] = (unsigned short)bf16_rne(f0.z); a0.s[3] = (unsigned short)bf16_rne(f0.w);
            a0.s[4] = (unsigned short)bf16_rne(f1.x); a0.s[5] = (unsigned short)bf16_rne(f1.y);
            a0.s[6] = (unsigned short)bf16_rne(f1.z); a0.s[7] = (unsigned short)bf16_rne(f1.w);
            a1.s[0] = (unsigned short)bf16_rne(f2.x); a1.s[1] = (unsigned short)bf16_rne(f2.y);
            a1.s[2] = (unsigned short)bf16_rne(f2.z); a1.s[3] = (unsigned short)bf16_rne(f2.w);
            a1.s[4] = (unsigned short)bf16_rne(f3.x); a1.s[5] = (unsigned short)bf16_rne(f3.y);
            a1.s[6] = (unsigned short)bf16_rne(f3.z); a1.s[7] = (unsigned short)bf16_rne(f3.w);
            A0 = a0.v; A1 = a1.v;
        }
        float dvm = dinv[rowA];

        f32x4 acc[4];
        #pragma unroll
        for (int ct = 0; ct < 4; ct++) acc[ct] = (f32x4){0.f, 0.f, 0.f, 0.f};
        #pragma unroll
        for (int ct = 0; ct < 4; ct++) {
            acc[ct] = __builtin_amdgcn_mfma_f32_16x16x32_bf16(A0, Bf[0][ct], acc[ct], 0, 0, 0);
            acc[ct] = __builtin_amdgcn_mfma_f32_16x16x32_bf16(A1, Bf[1][ct], acc[ct], 0, 0, 0);
        }

        #pragma unroll
        for (int reg = 0; reg < 4; reg++) {
            int r = kq * 4 + reg;
            float dv = __shfl(dvm, r);  // lane r holds dinv[row0+r]
            #pragma unroll
            for (int ct = 0; ct < 4; ct++) {
                outT[r * 66 + ct * 16 + nn] = acc[ct][reg] * dv;
            }
        }
        int rr = lane >> 2;        // 4 lanes per row
        int c0 = (lane & 3) * 16;  // 16 cols per lane
        int orow = row0 + rr;
        if (orow < N) {
            unsigned pk[8];
            #pragma unroll
            for (int i = 0; i < 8; i++) {
                float lo = outT[rr * 66 + c0 + 2 * i];
                float hi = outT[rr * 66 + c0 + 2 * i + 1];
                pk[i] = bf16_rne(lo) | (bf16_rne(hi) << 16);
            }
            uint4* dst = (uint4*)Hout + (size_t)orow * 8 + (lane & 3) * 2;
            dst[0] = make_uint4(pk[0], pk[1], pk[2], pk[3]);
            dst[1] = make_uint4(pk[4], pk[5], pk[6], pk[7]);
        }
    }
}

// out[v] = epi( dinv[v] * sum_{j in CSR[v]} H[src_j] + bias )
// 8 lanes x uint4 per edge: el=lane>>3 (edge slot), fl=lane&7 (feats 8fl..+7).
// 2x unroll -> 16 edges in flight per iteration.
template <bool RELU_BF16OUT>
__global__ __launch_bounds__(256) void k_agg(const uint4* __restrict__ H,
                                             const int* __restrict__ offsets,
                                             const int* __restrict__ cnt,
                                             const int* __restrict__ csrc,
                                             const float* __restrict__ dinv,
                                             const float* __restrict__ bias,
                                             void* __restrict__ outv, int N) {
    int t = threadIdx.x;
    int lane = t & 63;
    int el = lane >> 3;   // edge slot 0..7
    int fl = lane & 7;    // feature group: feats 8*fl .. 8*fl+7
    int v = blockIdx.x * WPB + (t >> 6);
    if (v >= N) return;
    int beg = offsets[v];
    int deg = cnt[v];
    float a0 = 0.f, a1 = 0.f, a2 = 0.f, a3 = 0.f;
    float a4 = 0.f, a5 = 0.f, a6 = 0.f, a7 = 0.f;
    for (int j = 0; j < deg; j += 16) {
        int e0 = j + el;
        int e1 = j + 8 + el;
        int s0 = (e0 < deg) ? csrc[beg + e0] : -1;
        int s1 = (e1 < deg) ? csrc[beg + e1] : -1;
        if (s0 >= 0) {
            uint4 d = H[(size_t)s0 * 8 + fl];
            a0 += bf16_lo(d.x); a1 += bf16_hi(d.x);
            a2 += bf16_lo(d.y); a3 += bf16_hi(d.y);
            a4 += bf16_lo(d.z); a5 += bf16_hi(d.z);
            a6 += bf16_lo(d.w); a7 += bf16_hi(d.w);
        }
        if (s1 >= 0) {
            uint4 d = H[(size_t)s1 * 8 + fl];
            a0 += bf16_lo(d.x); a1 += bf16_hi(d.x);
            a2 += bf16_lo(d.y); a3 += bf16_hi(d.y);
            a4 += bf16_lo(d.z); a5 += bf16_hi(d.z);
            a6 += bf16_lo(d.w); a7 += bf16_hi(d.w);
        }
    }
    // reduce across the 8 edge slots (strides 8, 16, 32)
    #pragma unroll
    for (int d = 8; d < 64; d <<= 1) {
        a0 += __shfl_xor(a0, d); a1 += __shfl_xor(a1, d);
        a2 += __shfl_xor(a2, d); a3 += __shfl_xor(a3, d);
        a4 += __shfl_xor(a4, d); a5 += __shfl_xor(a5, d);
        a6 += __shfl_xor(a6, d); a7 += __shfl_xor(a7, d);
    }
    if (el == 0) {
        int f = fl * 8;
        float dv = dinv[v];
        float r0 = fmaf(dv, a0, bias[f + 0]);
        float r1 = fmaf(dv, a1, bias[f + 1]);
        float r2 = fmaf(dv, a2, bias[f + 2]);
        float r3 = fmaf(dv, a3, bias[f + 3]);
        float r4 = fmaf(dv, a4, bias[f + 4]);
        float r5 = fmaf(dv, a5, bias[f + 5]);
        float r6 = fmaf(dv, a6, bias[f + 6]);
        float r7 = fmaf(dv, a7, bias[f + 7]);
        if (RELU_BF16OUT) {
            r0 = fmaxf(r0, 0.f); r1 = fmaxf(r1, 0.f);
            r2 = fmaxf(r2, 0.f); r3 = fmaxf(r3, 0.f);
            r4 = fmaxf(r4, 0.f); r5 = fmaxf(r5, 0.f);
            r6 = fmaxf(r6, 0.f); r7 = fmaxf(r7, 0.f);
            uint4 pk;
            pk.x = bf16_rne(r0) | (bf16_rne(r1) << 16);
            pk.y = bf16_rne(r2) | (bf16_rne(r3) << 16);
            pk.z = bf16_rne(r4) | (bf16_rne(r5) << 16);
            pk.w = bf16_rne(r6) | (bf16_rne(r7) << 16);
            ((uint4*)outv)[(size_t)v * 8 + fl] = pk;
        } else {
            float4* o = (float4*)outv + (size_t)v * 16 + fl * 2;
            o[0] = make_float4(r0, r1, r2, r3);
            o[1] = make_float4(r4, r5, r6, r7);
        }
    }
}

extern "C" void kernel_launch(void* const* d_in, const int* in_sizes, int n_in,
                              void* d_out, int out_size, void* d_ws, size_t ws_size,
                              hipStream_t stream) {
    const float* x  = (const float*)d_in[0];
    const int*   ei = (const int*)d_in[1];  // harness delivers int32
    const float* W1 = (const float*)d_in[2];
    const float* b1 = (const float*)d_in[3];
    const float* W2 = (const float*)d_in[4];
    const float* b2 = (const float*)d_in[5];
    float* out      = (float*)d_out;

    const int N = in_sizes[0] / 64;
    const int E = in_sizes[1] / 2;
    const int* row = ei;
    const int* col = ei + E;
    const int T = E + N;
    const int NB = (N + BSZ - 1) >> BSH;  // buckets

    char* p = (char*)d_ws;
    auto alloc = [&](size_t bytes) { void* r = (void*)p; p += (bytes + 255) & ~(size_t)255; return r; };
    int*      bcnt    = (int*)alloc((size_t)(NB + 1) * 4);
    int*      boff    = (int*)alloc((size_t)(NB + 1) * 4);
    int*      bcur    = (int*)alloc((size_t)(NB + 1) * 4);
    int*      offsets = (int*)alloc((size_t)N * 4);
    int*      cnt     = (int*)alloc((size_t)N * 4);
    float*    dinv    = (float*)alloc((size_t)N * 4);
    unsigned* pairs   = (unsigned*)alloc((size_t)T * 4);
    int*      csrc    = (int*)alloc((size_t)T * 4);
    unsigned* hbuf    = (unsigned*)alloc((size_t)N * 32 * 4);  // bf16 packed
    unsigned* abuf    = (unsigned*)alloc((size_t)N * 32 * 4);  // bf16 packed

    const int numTiles = (T + PTILE - 1) / PTILE;

    k_binit<<<(NB + 511) / 512, 512, 0, stream>>>(bcnt, NB, N);
    k_bcount<<<512, 256, 0, stream>>>(col, E, bcnt, NB);
    k_bscan<<<1, 512, 0, stream>>>(bcnt, NB, boff, bcur);
    k_part<<<numTiles, 256, 0, stream>>>(row, col, E, N, NB, numTiles, bcur, pairs);
    k_bfill<<<NB, 256, 0, stream>>>(pairs, boff, N, offsets, cnt, dinv, csrc);

    const int nSlabs = (N + 15) / 16;
    const int GEMM_BLOCKS = 512;                 // 4 waves each
    const int SLAB_STRIDE = GEMM_BLOCKS * 4;
    const int GB = (N + WPB - 1) / WPB;

    k_gemm<false><<<GEMM_BLOCKS, 256, 0, stream>>>(x, W1, dinv, hbuf, N, nSlabs, SLAB_STRIDE);
    k_agg<true><<<GB, 256, 0, stream>>>((const uint4*)hbuf, offsets, cnt, csrc, dinv, b1, abuf, N);
    k_gemm<true><<<GEMM_BLOCKS, 256, 0, stream>>>(abuf, W2, dinv, hbuf, N, nSlabs, SLAB_STRIDE);
    k_agg<false><<<GB, 256, 0, stream>>>((const uint4*)hbuf, offsets, cnt, csrc, dinv, b2, out, N);
}